// Round 7
// baseline (529.203 us; speedup 1.0000x reference)
//
#include <hip/hip_runtime.h>
#include <hip/hip_bf16.h>

// Problem dims (fixed): B=64, Te=1024, De=Dd=H=1024.
#define B_  64
#define TE  1024
#define K_  1024
#define HH  1024
#define MM  (B_ * TE)

typedef __bf16 bf16x8 __attribute__((ext_vector_type(8)));
typedef __bf16 bf16x4 __attribute__((ext_vector_type(4)));
typedef float  f32x4  __attribute__((ext_vector_type(4)));

__device__ __forceinline__ float fast_tanh(float x) {
    // tanh(x) = sign(x) * (1 - e^{-2|x|}) / (1 + e^{-2|x|}); branch-free, no overflow.
    float ax = __builtin_fabsf(x);
    float t  = __expf(-2.0f * ax);
    float r  = (1.0f - t) * __builtin_amdgcn_rcpf(1.0f + t);
    return __builtin_copysignf(r, x);
}

// ---------------------------------------------------------------- prep: cvt(Ua_w) + Wa GEMV + zero(scores,out)
// blocks 0..255: fp32->bf16 convert of Ua_w, plus zeroing of scores and out
// (both 16384 f32x4 -- replaces two memset dispatches).
// blocks 256..1279: Wa[b,h] = dec[b]·Wa_w[h] + Wa_b[h].
__global__ __launch_bounds__(256) void prep_kernel(const float* __restrict__ Ua_w,
                                                   __bf16* __restrict__ uawB,
                                                   const float* __restrict__ dec,
                                                   const float* __restrict__ Wa_w,
                                                   const float* __restrict__ Wa_b,
                                                   float* __restrict__ WaOut,
                                                   float* __restrict__ scores,
                                                   float* __restrict__ outZ) {
    int bid = blockIdx.x, tid = threadIdx.x;
    if (bid < 256) {
        long zi = (long)bid * 256 + tid;             // 65536 threads; first 16384 zero both
        if (zi < MM / 4) {
            ((f32x4*)scores)[zi] = f32x4{0.f, 0.f, 0.f, 0.f};
            ((f32x4*)outZ)[zi]   = f32x4{0.f, 0.f, 0.f, 0.f};
        }
        const long n4 = (long)HH * 1024 / 4;
        const float4* in4 = (const float4*)Ua_w;
        bf16x4* out4 = (bf16x4*)uawB;
        for (long j = bid * 256 + tid; j < n4; j += 65536) {
            float4 v = in4[j];
            bf16x4 o;
            o[0] = (__bf16)v.x; o[1] = (__bf16)v.y; o[2] = (__bf16)v.z; o[3] = (__bf16)v.w;
            out4[j] = o;
        }
        return;
    }
    int wb = bid - 256;
    int b = wb >> 4, hc = wb & 15;
    int wave = tid >> 6, lane = tid & 63;

    const float4* d4 = (const float4*)(dec + b * 1024);
    float4 dreg[4];
    #pragma unroll
    for (int j = 0; j < 4; j++) dreg[j] = d4[lane * 4 + j];

    #pragma unroll 4
    for (int i = 0; i < 16; i++) {
        int h = hc * 64 + wave * 16 + i;
        const float4* wr = (const float4*)(Wa_w + (long)h * 1024);
        float a = 0.0f;
        #pragma unroll
        for (int j = 0; j < 4; j++) {
            float4 v = wr[lane * 4 + j];
            a += v.x * dreg[j].x + v.y * dreg[j].y + v.z * dreg[j].z + v.w * dreg[j].w;
        }
        #pragma unroll
        for (int off = 32; off > 0; off >>= 1)
            a += __shfl_xor(a, off, 64);
        if (lane == 0) WaOut[b * 1024 + h] = a + Wa_b[h];
    }
}

// ---------------------------------------------------------------- fused score GEMM
// scores[m] += sum_h Va_w[h]*tanh(enc[m,:]·Ua_w[h,:] + Wa[b,h] + Ua_b[h])
// Proven 2-phase structure (654 TF plateau; 5 restructures all lost to it):
// 128x256 tile, KT=64 single-buffer, 2 barriers/K-step, 8-slot XOR swizzle,
// (256,2). Only change vs round-0: B gload_lds issued BEFORE the A cvt/ds_write
// (same barrier pair, disjoint LDS regions) so the 8 async loads fly under the
// cvt VALU work. y==0 blocks also emit the bf16 A tile to encB.
#define MT 128
#define NP 256
#define KT 64

__global__ __launch_bounds__(256, 2) void score_gemm(
    const float* __restrict__ Af,    // [MM][1024] enc fp32
    __bf16* __restrict__ encB,       // [MM][1024] bf16 out (written by y==0 blocks)
    const __bf16* __restrict__ Bm,   // [1024][1024] Ua_w bf16
    const float* __restrict__ Wa,    // [64][1024]
    const float* __restrict__ Ua_b,  // [1024]
    const float* __restrict__ Va_w,  // [1024]
    float* __restrict__ scores)      // [MM], pre-zeroed, atomic accumulate
{
    __shared__ __bf16 sA[MT * KT];   // 16 KB, swizzled: row r, slot s' holds seg s'^(r&7)
    __shared__ __bf16 sB[NP * KT];   // 32 KB
    __shared__ float sVa[NP];
    __shared__ float sWU[NP];

    const int tid  = threadIdx.x;
    const int wave = tid >> 6;
    const int lane = tid & 63;
    const int quad = lane >> 4;
    const int l16  = lane & 15;
    const int wm   = wave >> 1;      // 0..1 -> 64-row half
    const int wn   = wave & 1;       // 0..1 -> 128-col half

    // bid -> (x strip, y quarter); groups of 32 bids = 8 XCD slots x 4 y sharing x.
    const int bid = blockIdx.x;
    const int grp = bid >> 5;
    const int r5  = bid & 31;
    const int y   = r5 >> 3;
    const int x   = grp * 8 + (r5 & 7);

    const int rowBase = x * MT;
    const int colBase = y * NP;
    const int b       = rowBase >> 10;
    const bool wb     = (y == 0);    // this block writes the bf16 A strip

    if (tid < NP) {
        int h = colBase + tid;
        sVa[tid] = Va_w[h];
        sWU[tid] = Wa[b * 1024 + h] + Ua_b[h];
    }

    // My 4 A chunks (8 bf16 each): c = i*256+tid; r=c>>3; seg=(c&7)^(r&7)
    int rr[4], sg[4];
    #pragma unroll
    for (int i = 0; i < 4; i++) {
        int c = i * 256 + tid;
        rr[i] = c >> 3;
        sg[i] = (c & 7) ^ (rr[i] & 7);
    }

    f32x4 acc[4][8] = {};            // [m-subtile s][n-subtile t]

    const long aBase = (long)rowBase * K_;
    const long bBase = (long)colBase * K_;

    float4 pre[4][2];
    #pragma unroll
    for (int i = 0; i < 4; i++) {    // prefetch A(k0=0)
        const float4* p = (const float4*)(Af + aBase + (long)rr[i] * K_ + sg[i] * 8);
        pre[i][0] = p[0]; pre[i][1] = p[1];
    }

    for (int k0 = 0; k0 < K_; k0 += KT) {
        __syncthreads();             // prior ds_reads done; prefetch loads drained here
        #pragma unroll
        for (int i = 0; i < 8; i++) {            // B: issue async loads FIRST
            int c = i * 256 + tid;
            int r = c >> 3, slot = c & 7;
            int seg = slot ^ (r & 7);
            __builtin_amdgcn_global_load_lds(
                (const __attribute__((address_space(1))) unsigned int*)(Bm + bBase + (long)r * K_ + k0 + seg * 8),
                (__attribute__((address_space(3))) unsigned int*)(sB + c * 8), 16, 0, 0);
        }
        #pragma unroll
        for (int i = 0; i < 4; i++) {            // A: cvt + ds_write (+ optional writeback)
            bf16x8 v;
            v[0] = (__bf16)pre[i][0].x; v[1] = (__bf16)pre[i][0].y;
            v[2] = (__bf16)pre[i][0].z; v[3] = (__bf16)pre[i][0].w;
            v[4] = (__bf16)pre[i][1].x; v[5] = (__bf16)pre[i][1].y;
            v[6] = (__bf16)pre[i][1].z; v[7] = (__bf16)pre[i][1].w;
            *(bf16x8*)(sA + (i * 256 + tid) * 8) = v;
            if (wb)
                *(bf16x8*)(encB + aBase + (long)rr[i] * K_ + k0 + sg[i] * 8) = v;
        }
        __syncthreads();             // staged data visible

        if (k0 + KT < K_) {          // issue next A prefetch; hides under MFMA phase
            #pragma unroll
            for (int i = 0; i < 4; i++) {
                const float4* p = (const float4*)(Af + aBase + (long)rr[i] * K_ + (k0 + KT) + sg[i] * 8);
                pre[i][0] = p[0]; pre[i][1] = p[1];
            }
        }

        #pragma unroll
        for (int ks = 0; ks < 2; ks++) {
            bf16x8 bfr[8];
            #pragma unroll
            for (int t = 0; t < 8; t++) {
                int r = wn * 128 + t * 16 + l16;
                int slot = (ks * 4 + quad) ^ (r & 7);
                bfr[t] = *(const bf16x8*)(sB + r * KT + slot * 8);
            }
            #pragma unroll
            for (int s = 0; s < 4; s++) {
                int r = wm * 64 + s * 16 + l16;
                int slot = (ks * 4 + quad) ^ (r & 7);
                bf16x8 af = *(const bf16x8*)(sA + r * KT + slot * 8);
                #pragma unroll
                for (int t = 0; t < 8; t++)
                    acc[s][t] = __builtin_amdgcn_mfma_f32_16x16x32_bf16(af, bfr[t], acc[s][t], 0, 0, 0);
            }
        }
    }

    // Epilogue. C/D layout: row = quad*4 + reg, col = l16.
    float rs[4][4] = {};
    #pragma unroll
    for (int s = 0; s < 4; s++)
        #pragma unroll
        for (int t = 0; t < 8; t++) {
            int hl = wn * 128 + t * 16 + l16;
            float va = sVa[hl], wu = sWU[hl];
            #pragma unroll
            for (int r = 0; r < 4; r++)
                rs[s][r] += va * fast_tanh(acc[s][t][r] + wu);
        }

    #pragma unroll
    for (int s = 0; s < 4; s++)
        #pragma unroll
        for (int r = 0; r < 4; r++) {
            float v = rs[s][r];
            v += __shfl_xor(v, 1, 64);
            v += __shfl_xor(v, 2, 64);
            v += __shfl_xor(v, 4, 64);
            v += __shfl_xor(v, 8, 64);
            if (l16 == 0)
                atomicAdd(&scores[rowBase + wm * 64 + s * 16 + quad * 4 + r], v);
        }
}

// ---------------------------------------------------------------- context: softmax + partial dot + atomic out
// Block (b, ec): recompute softmax reduction over the full 1024-row (4 KB read,
// two shuffle reductions -- cheap, removes a dispatch), keep this block's 128
// weights in LDS, weights·enc partial dot, LDS pair-reduce, atomicAdd into out
// (pre-zeroed in prep; removes the context_reduce dispatch and pb round-trip).
__global__ __launch_bounds__(256) void context_kernel(const __bf16* __restrict__ enc,
                                                      const float* __restrict__ sc,
                                                      float* __restrict__ out) {
    __shared__ float red[2][128][8];     // 8 KB
    __shared__ float wLds[128];
    __shared__ float xr[8];
    int b = blockIdx.x, ec = blockIdx.y, tid = threadIdx.x;
    int wave = tid >> 6, lane = tid & 63;

    // ---- softmax over scores[b][:] (redundant per block) ----
    float4 v = ((const float4*)(sc + b * 1024))[tid];
    float m = fmaxf(fmaxf(v.x, v.y), fmaxf(v.z, v.w));
    #pragma unroll
    for (int off = 32; off > 0; off >>= 1)
        m = fmaxf(m, __shfl_xor(m, off, 64));
    if (lane == 0) xr[wave] = m;
    __syncthreads();
    m = fmaxf(fmaxf(xr[0], xr[1]), fmaxf(xr[2], xr[3]));
    float ex = expf(v.x - m), ey = expf(v.y - m), ez = expf(v.z - m), ew = expf(v.w - m);
    float sum = ex + ey + ez + ew;
    #pragma unroll
    for (int off = 32; off > 0; off >>= 1)
        sum += __shfl_xor(sum, off, 64);
    if (lane == 0) xr[4 + wave] = sum;
    __syncthreads();
    float inv = 1.0f / (xr[4] + xr[5] + xr[6] + xr[7]);
    // threads ec*32 .. ec*32+31 hold this block's 128 e-values (e = 4*tid .. 4*tid+3)
    int u = tid - ec * 32;
    if (u >= 0 && u < 32) {
        wLds[u * 4 + 0] = ex * inv;
        wLds[u * 4 + 1] = ey * inv;
        wLds[u * 4 + 2] = ez * inv;
        wLds[u * 4 + 3] = ew * inv;
    }
    __syncthreads();

    // ---- partial dot: e-rows ec*128..+128 ----
    int eo = tid >> 7;
    int dc = tid & 127;
    const bf16x8* enc8 = (const bf16x8*)(enc + ((long)b * 1024 + ec * 128) * 1024);
    float acc[8] = {};
    #pragma unroll 4
    for (int e = eo; e < 128; e += 2) {
        float we = wLds[e];              // same-address broadcast, conflict-free
        bf16x8 vv = enc8[e * 128 + dc];
        #pragma unroll
        for (int j = 0; j < 8; j++) acc[j] += we * (float)vv[j];
    }
    #pragma unroll
    for (int j = 0; j < 8; j++) red[eo][dc][j] = acc[j];
    __syncthreads();
    if (eo == 0) {
        float* o = out + b * 1024 + dc * 8;
        #pragma unroll
        for (int j = 0; j < 8; j++)
            atomicAdd(o + j, red[0][dc][j] + red[1][dc][j]);
    }
}

// ----------------------------------------------------------------
extern "C" void kernel_launch(void* const* d_in, const int* in_sizes, int n_in,
                              void* d_out, int out_size, void* d_ws, size_t ws_size,
                              hipStream_t stream) {
    (void)in_sizes; (void)n_in; (void)ws_size; (void)out_size;
    const float* enc   = (const float*)d_in[0];
    const float* dec   = (const float*)d_in[1];
    const float* Wa_w  = (const float*)d_in[2];
    const float* Wa_b  = (const float*)d_in[3];
    const float* Ua_w  = (const float*)d_in[4];
    const float* Ua_b  = (const float*)d_in[5];
    const float* Va_w  = (const float*)d_in[6];
    // d_in[7] = Va_b: softmax-invariant -> dropped.
    float* out = (float*)d_out;

    char* w = (char*)d_ws;
    __bf16* encB = (__bf16*)w;  w += (size_t)MM * 1024 * 2;
    __bf16* uawB = (__bf16*)w;  w += (size_t)HH * 1024 * 2;
    float* WaBuf = (float*)w;   w += (size_t)B_ * HH * 4;
    float* scores = (float*)w;  w += (size_t)MM * 4;

    // 3 dispatches: zeroing folded into prep, softmax+reduce folded into context.
    prep_kernel<<<dim3(256 + B_ * 16), 256, 0, stream>>>(Ua_w, uawB, dec, Wa_w, Wa_b, WaBuf, scores, out);
    score_gemm<<<dim3((MM / MT) * (HH / NP)), 256, 0, stream>>>(enc, encB, uawB, WaBuf, Ua_b, Va_w, scores);
    context_kernel<<<dim3(B_, 8), 256, 0, stream>>>(encB, scores, out);
}

// Round 8
// 522.799 us; speedup vs baseline: 1.0122x; 1.0122x over previous
//
#include <hip/hip_runtime.h>
#include <hip/hip_bf16.h>

// Problem dims (fixed): B=64, Te=1024, De=Dd=H=1024.
#define B_  64
#define TE  1024
#define K_  1024
#define HH  1024
#define MM  (B_ * TE)

typedef __bf16 bf16x8 __attribute__((ext_vector_type(8)));
typedef __bf16 bf16x4 __attribute__((ext_vector_type(4)));
typedef float  f32x4  __attribute__((ext_vector_type(4)));

__device__ __forceinline__ float fast_tanh(float x) {
    // tanh(x) = sign(x) * (1 - e^{-2|x|}) / (1 + e^{-2|x|}); branch-free, no overflow.
    float ax = __builtin_fabsf(x);
    float t  = __expf(-2.0f * ax);
    float r  = (1.0f - t) * __builtin_amdgcn_rcpf(1.0f + t);
    return __builtin_copysignf(r, x);
}

// ---------------------------------------------------------------- prep: cvt(Ua_w) + Wa GEMV + zero(scores)
// blocks 0..255: fp32->bf16 convert of Ua_w, plus zeroing of scores.
// blocks 256..1279: Wa[b,h] = dec[b]·Wa_w[h] + Wa_b[h].
__global__ __launch_bounds__(256) void prep_kernel(const float* __restrict__ Ua_w,
                                                   __bf16* __restrict__ uawB,
                                                   const float* __restrict__ dec,
                                                   const float* __restrict__ Wa_w,
                                                   const float* __restrict__ Wa_b,
                                                   float* __restrict__ WaOut,
                                                   float* __restrict__ scores) {
    int bid = blockIdx.x, tid = threadIdx.x;
    if (bid < 256) {
        long zi = (long)bid * 256 + tid;             // scores: 65536 floats = 16384 f32x4
        if (zi < MM / 4) ((f32x4*)scores)[zi] = f32x4{0.f, 0.f, 0.f, 0.f};
        const long n4 = (long)HH * 1024 / 4;
        const float4* in4 = (const float4*)Ua_w;
        bf16x4* out4 = (bf16x4*)uawB;
        for (long j = bid * 256 + tid; j < n4; j += 65536) {
            float4 v = in4[j];
            bf16x4 o;
            o[0] = (__bf16)v.x; o[1] = (__bf16)v.y; o[2] = (__bf16)v.z; o[3] = (__bf16)v.w;
            out4[j] = o;
        }
        return;
    }
    int wb = bid - 256;
    int b = wb >> 4, hc = wb & 15;
    int wave = tid >> 6, lane = tid & 63;

    const float4* d4 = (const float4*)(dec + b * 1024);
    float4 dreg[4];
    #pragma unroll
    for (int j = 0; j < 4; j++) dreg[j] = d4[lane * 4 + j];

    #pragma unroll 4
    for (int i = 0; i < 16; i++) {
        int h = hc * 64 + wave * 16 + i;
        const float4* wr = (const float4*)(Wa_w + (long)h * 1024);
        float a = 0.0f;
        #pragma unroll
        for (int j = 0; j < 4; j++) {
            float4 v = wr[lane * 4 + j];
            a += v.x * dreg[j].x + v.y * dreg[j].y + v.z * dreg[j].z + v.w * dreg[j].w;
        }
        #pragma unroll
        for (int off = 32; off > 0; off >>= 1)
            a += __shfl_xor(a, off, 64);
        if (lane == 0) WaOut[b * 1024 + h] = a + Wa_b[h];
    }
}

// ---------------------------------------------------------------- fused score GEMM
// scores[m] += sum_h Va_w[h]*tanh(enc[m,:]·Ua_w[h,:] + Wa[b,h] + Ua_b[h])
// Proven 2-phase structure (654 TF plateau): 128x256 tile, KT=64 single-buffer,
// 2 barriers/K-step, 8-slot XOR swizzle, (256,2), round-0/6 issue order
// (A cvt/ds_write first, then B gload_lds).
// Change vs R6: encB writeback DELETED -- its global stores sat inside the
// vmcnt(0) barrier drain for 1/4 of the blocks every K-step (WRITE_SIZE 139 MB).
// context now reads fp32 enc directly (L3-hot after this kernel streams it).
#define MT 128
#define NP 256
#define KT 64

__global__ __launch_bounds__(256, 2) void score_gemm(
    const float* __restrict__ Af,    // [MM][1024] enc fp32
    const __bf16* __restrict__ Bm,   // [1024][1024] Ua_w bf16
    const float* __restrict__ Wa,    // [64][1024]
    const float* __restrict__ Ua_b,  // [1024]
    const float* __restrict__ Va_w,  // [1024]
    float* __restrict__ scores)      // [MM], pre-zeroed, atomic accumulate
{
    __shared__ __bf16 sA[MT * KT];   // 16 KB, swizzled: row r, slot s' holds seg s'^(r&7)
    __shared__ __bf16 sB[NP * KT];   // 32 KB
    __shared__ float sVa[NP];
    __shared__ float sWU[NP];

    const int tid  = threadIdx.x;
    const int wave = tid >> 6;
    const int lane = tid & 63;
    const int quad = lane >> 4;
    const int l16  = lane & 15;
    const int wm   = wave >> 1;      // 0..1 -> 64-row half
    const int wn   = wave & 1;       // 0..1 -> 128-col half

    // bid -> (x strip, y quarter); groups of 32 bids = 8 XCD slots x 4 y sharing x.
    const int bid = blockIdx.x;
    const int grp = bid >> 5;
    const int r5  = bid & 31;
    const int y   = r5 >> 3;
    const int x   = grp * 8 + (r5 & 7);

    const int rowBase = x * MT;
    const int colBase = y * NP;
    const int b       = rowBase >> 10;

    if (tid < NP) {
        int h = colBase + tid;
        sVa[tid] = Va_w[h];
        sWU[tid] = Wa[b * 1024 + h] + Ua_b[h];
    }

    // My 4 A chunks (8 bf16 each): c = i*256+tid; r=c>>3; seg=(c&7)^(r&7)
    int rr[4], sg[4];
    #pragma unroll
    for (int i = 0; i < 4; i++) {
        int c = i * 256 + tid;
        rr[i] = c >> 3;
        sg[i] = (c & 7) ^ (rr[i] & 7);
    }

    f32x4 acc[4][8] = {};            // [m-subtile s][n-subtile t]

    const long aBase = (long)rowBase * K_;
    const long bBase = (long)colBase * K_;

    float4 pre[4][2];
    #pragma unroll
    for (int i = 0; i < 4; i++) {    // prefetch A(k0=0)
        const float4* p = (const float4*)(Af + aBase + (long)rr[i] * K_ + sg[i] * 8);
        pre[i][0] = p[0]; pre[i][1] = p[1];
    }

    for (int k0 = 0; k0 < K_; k0 += KT) {
        __syncthreads();             // prior ds_reads done; prefetch loads drained here
        #pragma unroll
        for (int i = 0; i < 4; i++) {            // A: cvt + ds_write
            bf16x8 v;
            v[0] = (__bf16)pre[i][0].x; v[1] = (__bf16)pre[i][0].y;
            v[2] = (__bf16)pre[i][0].z; v[3] = (__bf16)pre[i][0].w;
            v[4] = (__bf16)pre[i][1].x; v[5] = (__bf16)pre[i][1].y;
            v[6] = (__bf16)pre[i][1].z; v[7] = (__bf16)pre[i][1].w;
            *(bf16x8*)(sA + (i * 256 + tid) * 8) = v;
        }
        #pragma unroll
        for (int i = 0; i < 8; i++) {            // B: 256x64 = 2048 chunks via async LDS
            int c = i * 256 + tid;
            int r = c >> 3, slot = c & 7;
            int seg = slot ^ (r & 7);
            __builtin_amdgcn_global_load_lds(
                (const __attribute__((address_space(1))) unsigned int*)(Bm + bBase + (long)r * K_ + k0 + seg * 8),
                (__attribute__((address_space(3))) unsigned int*)(sB + c * 8), 16, 0, 0);
        }
        __syncthreads();             // staged data visible

        if (k0 + KT < K_) {          // issue next A prefetch; hides under MFMA phase
            #pragma unroll
            for (int i = 0; i < 4; i++) {
                const float4* p = (const float4*)(Af + aBase + (long)rr[i] * K_ + (k0 + KT) + sg[i] * 8);
                pre[i][0] = p[0]; pre[i][1] = p[1];
            }
        }

        #pragma unroll
        for (int ks = 0; ks < 2; ks++) {
            bf16x8 bfr[8];
            #pragma unroll
            for (int t = 0; t < 8; t++) {
                int r = wn * 128 + t * 16 + l16;
                int slot = (ks * 4 + quad) ^ (r & 7);
                bfr[t] = *(const bf16x8*)(sB + r * KT + slot * 8);
            }
            #pragma unroll
            for (int s = 0; s < 4; s++) {
                int r = wm * 64 + s * 16 + l16;
                int slot = (ks * 4 + quad) ^ (r & 7);
                bf16x8 af = *(const bf16x8*)(sA + r * KT + slot * 8);
                #pragma unroll
                for (int t = 0; t < 8; t++)
                    acc[s][t] = __builtin_amdgcn_mfma_f32_16x16x32_bf16(af, bfr[t], acc[s][t], 0, 0, 0);
            }
        }
    }

    // Epilogue. C/D layout: row = quad*4 + reg, col = l16.
    float rs[4][4] = {};
    #pragma unroll
    for (int s = 0; s < 4; s++)
        #pragma unroll
        for (int t = 0; t < 8; t++) {
            int hl = wn * 128 + t * 16 + l16;
            float va = sVa[hl], wu = sWU[hl];
            #pragma unroll
            for (int r = 0; r < 4; r++)
                rs[s][r] += va * fast_tanh(acc[s][t][r] + wu);
        }

    #pragma unroll
    for (int s = 0; s < 4; s++)
        #pragma unroll
        for (int r = 0; r < 4; r++) {
            float v = rs[s][r];
            v += __shfl_xor(v, 1, 64);
            v += __shfl_xor(v, 2, 64);
            v += __shfl_xor(v, 4, 64);
            v += __shfl_xor(v, 8, 64);
            if (l16 == 0)
                atomicAdd(&scores[rowBase + wm * 64 + s * 16 + quad * 4 + r], v);
        }
}

// ---------------------------------------------------------------- context partials + inline softmax
// Block (b, ec): recompute softmax reduction over the full 1024-row (4 KB read,
// two shuffle reductions), keep this block's 128 weights in LDS, then
// weights·enc partial dot from fp32 enc (L3-hot) -> pb. R6's pb+reduce scheme
// (proven faster than atomic-out).
__global__ __launch_bounds__(256) void context_partial(const float* __restrict__ enc,
                                                       const float* __restrict__ sc,
                                                       float* __restrict__ pb) {
    __shared__ float red[2][128][8];     // 8 KB
    __shared__ float wLds[128];
    __shared__ float xr[8];
    int b = blockIdx.x, ec = blockIdx.y, tid = threadIdx.x;
    int wave = tid >> 6, lane = tid & 63;

    // ---- softmax over scores[b][:] (redundant per block) ----
    float4 v = ((const float4*)(sc + b * 1024))[tid];
    float m = fmaxf(fmaxf(v.x, v.y), fmaxf(v.z, v.w));
    #pragma unroll
    for (int off = 32; off > 0; off >>= 1)
        m = fmaxf(m, __shfl_xor(m, off, 64));
    if (lane == 0) xr[wave] = m;
    __syncthreads();
    m = fmaxf(fmaxf(xr[0], xr[1]), fmaxf(xr[2], xr[3]));
    float ex = expf(v.x - m), ey = expf(v.y - m), ez = expf(v.z - m), ew = expf(v.w - m);
    float sum = ex + ey + ez + ew;
    #pragma unroll
    for (int off = 32; off > 0; off >>= 1)
        sum += __shfl_xor(sum, off, 64);
    if (lane == 0) xr[4 + wave] = sum;
    __syncthreads();
    float inv = 1.0f / (xr[4] + xr[5] + xr[6] + xr[7]);
    // threads ec*32 .. ec*32+31 hold this block's 128 e-values (e = 4*tid .. 4*tid+3)
    int u = tid - ec * 32;
    if (u >= 0 && u < 32) {
        wLds[u * 4 + 0] = ex * inv;
        wLds[u * 4 + 1] = ey * inv;
        wLds[u * 4 + 2] = ez * inv;
        wLds[u * 4 + 3] = ew * inv;
    }
    __syncthreads();

    // ---- partial dot: e-rows ec*128..+128, fp32 enc (32 B/lane/row) ----
    int eo = tid >> 7;
    int dc = tid & 127;
    const float4* enc4 = (const float4*)(enc + ((long)b * 1024 + ec * 128) * 1024);
    float acc[8] = {};
    #pragma unroll 4
    for (int e = eo; e < 128; e += 2) {
        float we = wLds[e];              // same-address broadcast, conflict-free
        float4 v0 = enc4[e * 256 + dc * 2];
        float4 v1 = enc4[e * 256 + dc * 2 + 1];
        acc[0] += we * v0.x; acc[1] += we * v0.y;
        acc[2] += we * v0.z; acc[3] += we * v0.w;
        acc[4] += we * v1.x; acc[5] += we * v1.y;
        acc[6] += we * v1.z; acc[7] += we * v1.w;
    }
    #pragma unroll
    for (int j = 0; j < 8; j++) red[eo][dc][j] = acc[j];
    __syncthreads();
    if (eo == 0) {
        float* o = pb + ((long)(b * 8 + ec)) * 1024 + dc * 8;
        #pragma unroll
        for (int j = 0; j < 8; j++) o[j] = red[0][dc][j] + red[1][dc][j];
    }
}

// out[b][:] = sum_ec pb[b][ec][:]
__global__ void context_reduce(const float* __restrict__ pb, float* __restrict__ out) {
    int b = blockIdx.x, tid = threadIdx.x;
    const f32x4* p4 = (const f32x4*)pb;
    f32x4 s = {0.f, 0.f, 0.f, 0.f};
    #pragma unroll
    for (int ec = 0; ec < 8; ec++)
        s += p4[(b * 8 + ec) * 256 + tid];
    ((f32x4*)out)[b * 256 + tid] = s;
}

// ----------------------------------------------------------------
extern "C" void kernel_launch(void* const* d_in, const int* in_sizes, int n_in,
                              void* d_out, int out_size, void* d_ws, size_t ws_size,
                              hipStream_t stream) {
    (void)in_sizes; (void)n_in; (void)ws_size; (void)out_size;
    const float* enc   = (const float*)d_in[0];
    const float* dec   = (const float*)d_in[1];
    const float* Wa_w  = (const float*)d_in[2];
    const float* Wa_b  = (const float*)d_in[3];
    const float* Ua_w  = (const float*)d_in[4];
    const float* Ua_b  = (const float*)d_in[5];
    const float* Va_w  = (const float*)d_in[6];
    // d_in[7] = Va_b: softmax-invariant -> dropped.
    float* out = (float*)d_out;

    char* w = (char*)d_ws;
    __bf16* uawB = (__bf16*)w;  w += (size_t)HH * 1024 * 2;
    float* WaBuf = (float*)w;   w += (size_t)B_ * HH * 4;
    float* scores = (float*)w;  w += (size_t)MM * 4;
    float* pb = (float*)w;      w += (size_t)B_ * 8 * 1024 * 4;

    // 4 dispatches; no encB buffer (context reads fp32 enc, L3-hot after score).
    prep_kernel<<<dim3(256 + B_ * 16), 256, 0, stream>>>(Ua_w, uawB, dec, Wa_w, Wa_b, WaBuf, scores);
    score_gemm<<<dim3((MM / MT) * (HH / NP)), 256, 0, stream>>>(enc, uawB, WaBuf, Ua_b, Va_w, scores);
    context_partial<<<dim3(B_, 8), 256, 0, stream>>>(enc, scores, pb);
    context_reduce<<<dim3(B_), 256, 0, stream>>>(pb, out);
}

// Round 9
// 510.408 us; speedup vs baseline: 1.0368x; 1.0243x over previous
//
#include <hip/hip_runtime.h>
#include <hip/hip_bf16.h>

// Problem dims (fixed): B=64, Te=1024, De=Dd=H=1024.
#define B_  64
#define TE  1024
#define K_  1024
#define HH  1024
#define MM  (B_ * TE)

typedef __bf16 bf16x8 __attribute__((ext_vector_type(8)));
typedef __bf16 bf16x4 __attribute__((ext_vector_type(4)));
typedef float  f32x4  __attribute__((ext_vector_type(4)));

__device__ __forceinline__ float fast_tanh(float x) {
    // tanh(x) = sign(x) * (1 - e^{-2|x|}) / (1 + e^{-2|x|}); branch-free, no overflow.
    float ax = __builtin_fabsf(x);
    float t  = __expf(-2.0f * ax);
    float r  = (1.0f - t) * __builtin_amdgcn_rcpf(1.0f + t);
    return __builtin_copysignf(r, x);
}

// ---------------------------------------------------------------- prep: cvt(Ua_w) + Wa GEMV + zero(scores)
// blocks 0..255: fp32->bf16 convert of Ua_w, plus zeroing of scores.
// blocks 256..1279: Wa[b,h] = dec[b]·Wa_w[h] + Wa_b[h].
__global__ __launch_bounds__(256) void prep_kernel(const float* __restrict__ Ua_w,
                                                   __bf16* __restrict__ uawB,
                                                   const float* __restrict__ dec,
                                                   const float* __restrict__ Wa_w,
                                                   const float* __restrict__ Wa_b,
                                                   float* __restrict__ WaOut,
                                                   float* __restrict__ scores) {
    int bid = blockIdx.x, tid = threadIdx.x;
    if (bid < 256) {
        long zi = (long)bid * 256 + tid;             // scores: 65536 floats = 16384 f32x4
        if (zi < MM / 4) ((f32x4*)scores)[zi] = f32x4{0.f, 0.f, 0.f, 0.f};
        const long n4 = (long)HH * 1024 / 4;
        const float4* in4 = (const float4*)Ua_w;
        bf16x4* out4 = (bf16x4*)uawB;
        for (long j = bid * 256 + tid; j < n4; j += 65536) {
            float4 v = in4[j];
            bf16x4 o;
            o[0] = (__bf16)v.x; o[1] = (__bf16)v.y; o[2] = (__bf16)v.z; o[3] = (__bf16)v.w;
            out4[j] = o;
        }
        return;
    }
    int wb = bid - 256;
    int b = wb >> 4, hc = wb & 15;
    int wave = tid >> 6, lane = tid & 63;

    const float4* d4 = (const float4*)(dec + b * 1024);
    float4 dreg[4];
    #pragma unroll
    for (int j = 0; j < 4; j++) dreg[j] = d4[lane * 4 + j];

    #pragma unroll 4
    for (int i = 0; i < 16; i++) {
        int h = hc * 64 + wave * 16 + i;
        const float4* wr = (const float4*)(Wa_w + (long)h * 1024);
        float a = 0.0f;
        #pragma unroll
        for (int j = 0; j < 4; j++) {
            float4 v = wr[lane * 4 + j];
            a += v.x * dreg[j].x + v.y * dreg[j].y + v.z * dreg[j].z + v.w * dreg[j].w;
        }
        #pragma unroll
        for (int off = 32; off > 0; off >>= 1)
            a += __shfl_xor(a, off, 64);
        if (lane == 0) WaOut[b * 1024 + h] = a + Wa_b[h];
    }
}

// ---------------------------------------------------------------- fused score GEMM
// scores[m] += sum_h Va_w[h]*tanh(enc[m,:]·Ua_w[h,:] + Wa[b,h] + Ua_b[h])
// Proven 2-phase structure (654-690 TF plateau): 128x256 tile, KT=64 single-
// buffer, 2 barriers/K-step, 8-slot XOR swizzle, (256,2), A-cvt-first order.
// Change vs R6: encB writeback k-SPLIT across y-blocks -- block y writes only
// K-steps with (k0>>6)&3==y (4 interleaved steps each) instead of y==0 writing
// all 16. Same 134 MB total, but store-drain straggle spread over all blocks
// (R8 showed concentrated writeback costs ~12 us of barrier-drain straggle).
#define MT 128
#define NP 256
#define KT 64

__global__ __launch_bounds__(256, 2) void score_gemm(
    const float* __restrict__ Af,    // [MM][1024] enc fp32
    __bf16* __restrict__ encB,       // [MM][1024] bf16 out (k-split across y-blocks)
    const __bf16* __restrict__ Bm,   // [1024][1024] Ua_w bf16
    const float* __restrict__ Wa,    // [64][1024]
    const float* __restrict__ Ua_b,  // [1024]
    const float* __restrict__ Va_w,  // [1024]
    float* __restrict__ scores)      // [MM], pre-zeroed, atomic accumulate
{
    __shared__ __bf16 sA[MT * KT];   // 16 KB, swizzled: row r, slot s' holds seg s'^(r&7)
    __shared__ __bf16 sB[NP * KT];   // 32 KB
    __shared__ float sVa[NP];
    __shared__ float sWU[NP];

    const int tid  = threadIdx.x;
    const int wave = tid >> 6;
    const int lane = tid & 63;
    const int quad = lane >> 4;
    const int l16  = lane & 15;
    const int wm   = wave >> 1;      // 0..1 -> 64-row half
    const int wn   = wave & 1;       // 0..1 -> 128-col half

    // bid -> (x strip, y quarter); groups of 32 bids = 8 XCD slots x 4 y sharing x.
    const int bid = blockIdx.x;
    const int grp = bid >> 5;
    const int r5  = bid & 31;
    const int y   = r5 >> 3;
    const int x   = grp * 8 + (r5 & 7);

    const int rowBase = x * MT;
    const int colBase = y * NP;
    const int b       = rowBase >> 10;

    if (tid < NP) {
        int h = colBase + tid;
        sVa[tid] = Va_w[h];
        sWU[tid] = Wa[b * 1024 + h] + Ua_b[h];
    }

    // My 4 A chunks (8 bf16 each): c = i*256+tid; r=c>>3; seg=(c&7)^(r&7)
    int rr[4], sg[4];
    #pragma unroll
    for (int i = 0; i < 4; i++) {
        int c = i * 256 + tid;
        rr[i] = c >> 3;
        sg[i] = (c & 7) ^ (rr[i] & 7);
    }

    f32x4 acc[4][8] = {};            // [m-subtile s][n-subtile t]

    const long aBase = (long)rowBase * K_;
    const long bBase = (long)colBase * K_;

    float4 pre[4][2];
    #pragma unroll
    for (int i = 0; i < 4; i++) {    // prefetch A(k0=0)
        const float4* p = (const float4*)(Af + aBase + (long)rr[i] * K_ + sg[i] * 8);
        pre[i][0] = p[0]; pre[i][1] = p[1];
    }

    for (int k0 = 0; k0 < K_; k0 += KT) {
        const bool wb = (((k0 >> 6) & 3) == y);  // this block writes this k-slice
        __syncthreads();             // prior ds_reads done; prefetch loads drained here
        #pragma unroll
        for (int i = 0; i < 4; i++) {            // A: cvt + ds_write (+ k-split writeback)
            bf16x8 v;
            v[0] = (__bf16)pre[i][0].x; v[1] = (__bf16)pre[i][0].y;
            v[2] = (__bf16)pre[i][0].z; v[3] = (__bf16)pre[i][0].w;
            v[4] = (__bf16)pre[i][1].x; v[5] = (__bf16)pre[i][1].y;
            v[6] = (__bf16)pre[i][1].z; v[7] = (__bf16)pre[i][1].w;
            *(bf16x8*)(sA + (i * 256 + tid) * 8) = v;
            if (wb)
                *(bf16x8*)(encB + aBase + (long)rr[i] * K_ + k0 + sg[i] * 8) = v;
        }
        #pragma unroll
        for (int i = 0; i < 8; i++) {            // B: 256x64 = 2048 chunks via async LDS
            int c = i * 256 + tid;
            int r = c >> 3, slot = c & 7;
            int seg = slot ^ (r & 7);
            __builtin_amdgcn_global_load_lds(
                (const __attribute__((address_space(1))) unsigned int*)(Bm + bBase + (long)r * K_ + k0 + seg * 8),
                (__attribute__((address_space(3))) unsigned int*)(sB + c * 8), 16, 0, 0);
        }
        __syncthreads();             // staged data visible

        if (k0 + KT < K_) {          // issue next A prefetch; hides under MFMA phase
            #pragma unroll
            for (int i = 0; i < 4; i++) {
                const float4* p = (const float4*)(Af + aBase + (long)rr[i] * K_ + (k0 + KT) + sg[i] * 8);
                pre[i][0] = p[0]; pre[i][1] = p[1];
            }
        }

        #pragma unroll
        for (int ks = 0; ks < 2; ks++) {
            bf16x8 bfr[8];
            #pragma unroll
            for (int t = 0; t < 8; t++) {
                int r = wn * 128 + t * 16 + l16;
                int slot = (ks * 4 + quad) ^ (r & 7);
                bfr[t] = *(const bf16x8*)(sB + r * KT + slot * 8);
            }
            #pragma unroll
            for (int s = 0; s < 4; s++) {
                int r = wm * 64 + s * 16 + l16;
                int slot = (ks * 4 + quad) ^ (r & 7);
                bf16x8 af = *(const bf16x8*)(sA + r * KT + slot * 8);
                #pragma unroll
                for (int t = 0; t < 8; t++)
                    acc[s][t] = __builtin_amdgcn_mfma_f32_16x16x32_bf16(af, bfr[t], acc[s][t], 0, 0, 0);
            }
        }
    }

    // Epilogue. C/D layout: row = quad*4 + reg, col = l16.
    float rs[4][4] = {};
    #pragma unroll
    for (int s = 0; s < 4; s++)
        #pragma unroll
        for (int t = 0; t < 8; t++) {
            int hl = wn * 128 + t * 16 + l16;
            float va = sVa[hl], wu = sWU[hl];
            #pragma unroll
            for (int r = 0; r < 4; r++)
                rs[s][r] += va * fast_tanh(acc[s][t][r] + wu);
        }

    #pragma unroll
    for (int s = 0; s < 4; s++)
        #pragma unroll
        for (int r = 0; r < 4; r++) {
            float v = rs[s][r];
            v += __shfl_xor(v, 1, 64);
            v += __shfl_xor(v, 2, 64);
            v += __shfl_xor(v, 4, 64);
            v += __shfl_xor(v, 8, 64);
            if (l16 == 0)
                atomicAdd(&scores[rowBase + wm * 64 + s * 16 + quad * 4 + r], v);
        }
}

// ---------------------------------------------------------------- context partials + inline softmax
// Block (b, ec): recompute softmax reduction over the full 1024-row (4 KB read,
// two shuffle reductions), keep this block's 128 weights in LDS, then
// weights·encB (bf16, half the bytes of fp32 enc) partial dot -> pb.
__global__ __launch_bounds__(256) void context_partial(const __bf16* __restrict__ enc,
                                                       const float* __restrict__ sc,
                                                       float* __restrict__ pb) {
    __shared__ float red[2][128][8];     // 8 KB
    __shared__ float wLds[128];
    __shared__ float xr[8];
    int b = blockIdx.x, ec = blockIdx.y, tid = threadIdx.x;
    int wave = tid >> 6, lane = tid & 63;

    // ---- softmax over scores[b][:] (redundant per block) ----
    float4 v = ((const float4*)(sc + b * 1024))[tid];
    float m = fmaxf(fmaxf(v.x, v.y), fmaxf(v.z, v.w));
    #pragma unroll
    for (int off = 32; off > 0; off >>= 1)
        m = fmaxf(m, __shfl_xor(m, off, 64));
    if (lane == 0) xr[wave] = m;
    __syncthreads();
    m = fmaxf(fmaxf(xr[0], xr[1]), fmaxf(xr[2], xr[3]));
    float ex = expf(v.x - m), ey = expf(v.y - m), ez = expf(v.z - m), ew = expf(v.w - m);
    float sum = ex + ey + ez + ew;
    #pragma unroll
    for (int off = 32; off > 0; off >>= 1)
        sum += __shfl_xor(sum, off, 64);
    if (lane == 0) xr[4 + wave] = sum;
    __syncthreads();
    float inv = 1.0f / (xr[4] + xr[5] + xr[6] + xr[7]);
    // threads ec*32 .. ec*32+31 hold this block's 128 e-values (e = 4*tid .. 4*tid+3)
    int u = tid - ec * 32;
    if (u >= 0 && u < 32) {
        wLds[u * 4 + 0] = ex * inv;
        wLds[u * 4 + 1] = ey * inv;
        wLds[u * 4 + 2] = ez * inv;
        wLds[u * 4 + 3] = ew * inv;
    }
    __syncthreads();

    // ---- partial dot: e-rows ec*128..+128, bf16 enc (16 B/lane/row) ----
    int eo = tid >> 7;
    int dc = tid & 127;
    const bf16x8* enc8 = (const bf16x8*)(enc + ((long)b * 1024 + ec * 128) * 1024);
    float acc[8] = {};
    #pragma unroll 4
    for (int e = eo; e < 128; e += 2) {
        float we = wLds[e];              // same-address broadcast, conflict-free
        bf16x8 vv = enc8[e * 128 + dc];
        #pragma unroll
        for (int j = 0; j < 8; j++) acc[j] += we * (float)vv[j];
    }
    #pragma unroll
    for (int j = 0; j < 8; j++) red[eo][dc][j] = acc[j];
    __syncthreads();
    if (eo == 0) {
        float* o = pb + ((long)(b * 8 + ec)) * 1024 + dc * 8;
        #pragma unroll
        for (int j = 0; j < 8; j++) o[j] = red[0][dc][j] + red[1][dc][j];
    }
}

// out[b][:] = sum_ec pb[b][ec][:]
__global__ void context_reduce(const float* __restrict__ pb, float* __restrict__ out) {
    int b = blockIdx.x, tid = threadIdx.x;
    const f32x4* p4 = (const f32x4*)pb;
    f32x4 s = {0.f, 0.f, 0.f, 0.f};
    #pragma unroll
    for (int ec = 0; ec < 8; ec++)
        s += p4[(b * 8 + ec) * 256 + tid];
    ((f32x4*)out)[b * 256 + tid] = s;
}

// ----------------------------------------------------------------
extern "C" void kernel_launch(void* const* d_in, const int* in_sizes, int n_in,
                              void* d_out, int out_size, void* d_ws, size_t ws_size,
                              hipStream_t stream) {
    (void)in_sizes; (void)n_in; (void)ws_size; (void)out_size;
    const float* enc   = (const float*)d_in[0];
    const float* dec   = (const float*)d_in[1];
    const float* Wa_w  = (const float*)d_in[2];
    const float* Wa_b  = (const float*)d_in[3];
    const float* Ua_w  = (const float*)d_in[4];
    const float* Ua_b  = (const float*)d_in[5];
    const float* Va_w  = (const float*)d_in[6];
    // d_in[7] = Va_b: softmax-invariant -> dropped.
    float* out = (float*)d_out;

    char* w = (char*)d_ws;
    __bf16* encB = (__bf16*)w;  w += (size_t)MM * 1024 * 2;
    __bf16* uawB = (__bf16*)w;  w += (size_t)HH * 1024 * 2;
    float* WaBuf = (float*)w;   w += (size_t)B_ * HH * 4;
    float* scores = (float*)w;  w += (size_t)MM * 4;
    float* pb = (float*)w;      w += (size_t)B_ * 8 * 1024 * 4;

    // 4 dispatches: zeroing folded into prep; softmax folded into context.
    prep_kernel<<<dim3(256 + B_ * 16), 256, 0, stream>>>(Ua_w, uawB, dec, Wa_w, Wa_b, WaBuf, scores);
    score_gemm<<<dim3((MM / MT) * (HH / NP)), 256, 0, stream>>>(enc, encB, uawB, WaBuf, Ua_b, Va_w, scores);
    context_partial<<<dim3(B_, 8), 256, 0, stream>>>(encB, scores, pb);
    context_reduce<<<dim3(B_), 256, 0, stream>>>(pb, out);
}